// Round 1
// baseline (1141.028 us; speedup 1.0000x reference)
//
#include <hip/hip_runtime.h>

#define N_NODES 100000
#define N_EDGES 1600000
#define DIM 128
#define NGRAPH 64
#define SCAN_T 256
#define SCAN_BLK 1024
#define NSCAN_BLOCKS ((N_NODES + SCAN_BLK - 1) / SCAN_BLK)  // 98

// ---------------- CSR build ----------------

__global__ void k_count(const int* __restrict__ dst, int* __restrict__ cnt) {
    int e = blockIdx.x * blockDim.x + threadIdx.x;
    if (e < N_EDGES) atomicAdd(&cnt[dst[e]], 1);
}

__global__ void k_scan1(const int* __restrict__ cnt, int* __restrict__ rowptr,
                        int* __restrict__ bsum) {
    __shared__ int s[SCAN_T];
    int tid = threadIdx.x;
    int base = blockIdx.x * SCAN_BLK + tid * 4;
    int v0 = (base + 0 < N_NODES) ? cnt[base + 0] : 0;
    int v1 = (base + 1 < N_NODES) ? cnt[base + 1] : 0;
    int v2 = (base + 2 < N_NODES) ? cnt[base + 2] : 0;
    int v3 = (base + 3 < N_NODES) ? cnt[base + 3] : 0;
    int sum = v0 + v1 + v2 + v3;
    s[tid] = sum;
    __syncthreads();
    for (int off = 1; off < SCAN_T; off <<= 1) {
        int t = (tid >= off) ? s[tid - off] : 0;
        __syncthreads();
        s[tid] += t;
        __syncthreads();
    }
    int run = s[tid] - sum;  // exclusive prefix of this thread's 4 items
    if (base + 0 < N_NODES) rowptr[base + 0] = run; run += v0;
    if (base + 1 < N_NODES) rowptr[base + 1] = run; run += v1;
    if (base + 2 < N_NODES) rowptr[base + 2] = run; run += v2;
    if (base + 3 < N_NODES) rowptr[base + 3] = run;
    if (tid == SCAN_T - 1) bsum[blockIdx.x] = s[tid];
}

__global__ void k_scan2(int* __restrict__ bsum) {
    __shared__ int s[128];
    int tid = threadIdx.x;
    int v = (tid < NSCAN_BLOCKS) ? bsum[tid] : 0;
    s[tid] = v;
    __syncthreads();
    for (int off = 1; off < 128; off <<= 1) {
        int t = (tid >= off) ? s[tid - off] : 0;
        __syncthreads();
        s[tid] += t;
        __syncthreads();
    }
    if (tid < NSCAN_BLOCKS) bsum[tid] = s[tid] - v;  // exclusive
}

__global__ void k_scan3(int* __restrict__ rowptr, const int* __restrict__ bsum) {
    int tid = threadIdx.x;
    int base = blockIdx.x * SCAN_BLK + tid * 4;
    int add = bsum[blockIdx.x];
#pragma unroll
    for (int j = 0; j < 4; j++)
        if (base + j < N_NODES) rowptr[base + j] += add;
    if (blockIdx.x == 0 && tid == 0) rowptr[N_NODES] = N_EDGES;
}

__global__ void k_fill(const int* __restrict__ src, const int* __restrict__ dst,
                       const int* __restrict__ rowptr, int* __restrict__ cursor,
                       int* __restrict__ col) {
    int e = blockIdx.x * blockDim.x + threadIdx.x;
    if (e >= N_EDGES) return;
    int d = dst[e];
    int pos = rowptr[d] + atomicAdd(&cursor[d], 1);
    col[pos] = src[e];
}

// ---------------- mean aggregation (one wave per node) ----------------

__global__ void k_gather(const float* __restrict__ hin, const int* __restrict__ rowptr,
                         const int* __restrict__ col, float* __restrict__ aggn) {
    int lane = threadIdx.x & 63;
    int node = blockIdx.x * 4 + (threadIdx.x >> 6);
    int start = rowptr[node], end = rowptr[node + 1];
    float ax = 0.f, ay = 0.f;
    for (int c = start; c < end; c += 64) {
        int nl = end - c; if (nl > 64) nl = 64;
        int cv = (c + lane < end) ? col[c + lane] : 0;
        for (int j = 0; j < nl; j++) {
            int sidx = __shfl(cv, j);
            const float2 v = *(const float2*)(hin + (size_t)sidx * DIM + 2 * lane);
            ax += v.x; ay += v.y;
        }
    }
    int deg = end - start;
    float scale = 1.f / (float)(deg > 0 ? deg : 1);
    float2 o; o.x = ax * scale; o.y = ay * scale;
    *(float2*)(aggn + (size_t)node * DIM + 2 * lane) = o;
}

// ---------------- fused linear: out = act(aggn@Wl + bl + hin@Wr) ----------------
// block = 256 threads -> 32 rows x 128 cols, 4x4 register tile per thread.
// s_a/s_x staged k-major with pad 36 (aligned b128 reads, conflict-free).

template <bool RELU>
__global__ __launch_bounds__(256) void k_linear(
    const float* __restrict__ aggn, const float* __restrict__ hin,
    const float* __restrict__ Wl, const float* __restrict__ bl,
    const float* __restrict__ Wr, float* __restrict__ hout) {
    __shared__ float s_a[DIM][36];
    __shared__ float s_x[DIM][36];
    __shared__ float s_w[2][16][DIM];
    int tid = threadIdx.x;
    int i0 = blockIdx.x * 32;
#pragma unroll
    for (int t = 0; t < 4; t++) {
        int f = tid + t * 256;          // float4 id, 0..1023
        int r = f >> 5, kg = f & 31;
        float4 va = *(const float4*)(aggn + (size_t)(i0 + r) * DIM + kg * 4);
        float4 vx = *(const float4*)(hin + (size_t)(i0 + r) * DIM + kg * 4);
        s_a[kg * 4 + 0][r] = va.x; s_a[kg * 4 + 1][r] = va.y;
        s_a[kg * 4 + 2][r] = va.z; s_a[kg * 4 + 3][r] = va.w;
        s_x[kg * 4 + 0][r] = vx.x; s_x[kg * 4 + 1][r] = vx.y;
        s_x[kg * 4 + 2][r] = vx.z; s_x[kg * 4 + 3][r] = vx.w;
    }
    int jg = tid & 31, rg = tid >> 5;
    int j0 = jg * 4, r0 = rg * 4;
    float acc[4][4];
#pragma unroll
    for (int r = 0; r < 4; r++)
#pragma unroll
        for (int c = 0; c < 4; c++) acc[r][c] = 0.f;

    for (int kc = 0; kc < DIM; kc += 16) {
        __syncthreads();
#pragma unroll
        for (int t = 0; t < 2; t++) {
            int f = tid + t * 256;      // 0..511
            int kk = f >> 5, jj = (f & 31) * 4;
            *(float4*)&s_w[0][kk][jj] = *(const float4*)(Wl + (size_t)(kc + kk) * DIM + jj);
            *(float4*)&s_w[1][kk][jj] = *(const float4*)(Wr + (size_t)(kc + kk) * DIM + jj);
        }
        __syncthreads();
#pragma unroll
        for (int kk = 0; kk < 16; kk++) {
            float4 af = *(const float4*)&s_a[kc + kk][r0];
            float4 xf = *(const float4*)&s_x[kc + kk][r0];
            float4 wl = *(const float4*)&s_w[0][kk][j0];
            float4 wr = *(const float4*)&s_w[1][kk][j0];
            float afv[4] = {af.x, af.y, af.z, af.w};
            float xfv[4] = {xf.x, xf.y, xf.z, xf.w};
            float wlv[4] = {wl.x, wl.y, wl.z, wl.w};
            float wrv[4] = {wr.x, wr.y, wr.z, wr.w};
#pragma unroll
            for (int r = 0; r < 4; r++)
#pragma unroll
                for (int c = 0; c < 4; c++)
                    acc[r][c] += afv[r] * wlv[c] + xfv[r] * wrv[c];
        }
    }
    float4 bias = *(const float4*)(bl + j0);
    float bv[4] = {bias.x, bias.y, bias.z, bias.w};
#pragma unroll
    for (int r = 0; r < 4; r++) {
        float4 o;
        float* op = &o.x;
#pragma unroll
        for (int c = 0; c < 4; c++) {
            float v = acc[r][c] + bv[c];
            if (RELU) v = fmaxf(v, 0.f);
            op[c] = v;
        }
        *(float4*)(hout + (size_t)(i0 + r0 + r) * DIM + j0) = o;
    }
}

// ---------------- per-graph mean pool (batch is sorted) ----------------

__global__ void k_pool(const float* __restrict__ h, const int* __restrict__ batch,
                       float* __restrict__ pooled, float* __restrict__ gcnt) {
    int tid = threadIdx.x;
    int d = tid & 127, half = tid >> 7;
    int n0 = blockIdx.x * 64 + half * 32;
    if (n0 >= N_NODES) return;
    int nend = n0 + 32; if (nend > N_NODES) nend = N_NODES;
    float acc = 0.f;
    int cur = batch[n0];
    int run = 0;
    for (int n = n0; n < nend; n++) {
        int g = batch[n];
        if (g != cur) {
            atomicAdd(&pooled[cur * DIM + d], acc);
            if (d == 0) atomicAdd(&gcnt[cur], (float)run);
            acc = 0.f; run = 0; cur = g;
        }
        acc += h[(size_t)n * DIM + d];
        run++;
    }
    atomicAdd(&pooled[cur * DIM + d], acc);
    if (d == 0) atomicAdd(&gcnt[cur], (float)run);
}

__global__ void k_final(const float* __restrict__ pooled, const float* __restrict__ gcnt,
                        const float* __restrict__ Wlin, const float* __restrict__ blin,
                        float* __restrict__ out) {
    int t = threadIdx.x;  // 128 threads
    int g = t >> 1, o = t & 1;
    float sum = 0.f;
#pragma unroll 8
    for (int k = 0; k < DIM; k++) sum += pooled[g * DIM + k] * Wlin[k * 2 + o];
    float c = gcnt[g];
    out[g * 2 + o] = sum / fmaxf(c, 1.f) + blin[o];
}

// ---------------- launch ----------------

static inline size_t align_up(size_t v, size_t a) { return (v + a - 1) & ~(a - 1); }

extern "C" void kernel_launch(void* const* d_in, const int* in_sizes, int n_in,
                              void* d_out, int out_size, void* d_ws, size_t ws_size,
                              hipStream_t stream) {
    const float* x    = (const float*)d_in[0];
    const int*   ei   = (const int*)d_in[1];
    const int*   src  = ei;
    const int*   dst  = ei + N_EDGES;
    const int*   batch = (const int*)d_in[2];
    const float* Wl1 = (const float*)d_in[3];
    const float* bl1 = (const float*)d_in[4];
    const float* Wr1 = (const float*)d_in[5];
    const float* Wl2 = (const float*)d_in[6];
    const float* bl2 = (const float*)d_in[7];
    const float* Wr2 = (const float*)d_in[8];
    const float* Wl3 = (const float*)d_in[9];
    const float* bl3 = (const float*)d_in[10];
    const float* Wr3 = (const float*)d_in[11];
    const float* Wlin = (const float*)d_in[12];
    const float* blin = (const float*)d_in[13];
    float* out = (float*)d_out;

    char* p = (char*)d_ws;
    size_t off = 0;
    auto carve = [&](size_t bytes) -> void* {
        void* r = p + off;
        off = align_up(off + bytes, 256);
        return r;
    };
    int* rowptr = (int*)carve((N_NODES + 1) * sizeof(int));
    int* cursor = (int*)carve(N_NODES * sizeof(int));
    int* bsum   = (int*)carve(128 * sizeof(int));
    int* col    = (int*)carve((size_t)N_EDGES * sizeof(int));
    float* aggn = (float*)carve((size_t)N_NODES * DIM * sizeof(float));
    float* hA   = (float*)carve((size_t)N_NODES * DIM * sizeof(float));
    float* hB   = (float*)carve((size_t)N_NODES * DIM * sizeof(float));
    float* pooled = (float*)carve((size_t)NGRAPH * DIM * sizeof(float));
    float* gcnt   = (float*)carve((size_t)NGRAPH * sizeof(float));

    // ---- CSR build ----
    hipMemsetAsync(cursor, 0, N_NODES * sizeof(int), stream);
    k_count<<<N_EDGES / 256, 256, 0, stream>>>(dst, cursor);
    k_scan1<<<NSCAN_BLOCKS, SCAN_T, 0, stream>>>(cursor, rowptr, bsum);
    k_scan2<<<1, 128, 0, stream>>>(bsum);
    k_scan3<<<NSCAN_BLOCKS, SCAN_T, 0, stream>>>(rowptr, bsum);
    hipMemsetAsync(cursor, 0, N_NODES * sizeof(int), stream);
    k_fill<<<N_EDGES / 256, 256, 0, stream>>>(src, dst, rowptr, cursor, col);

    // ---- layer 1 ----
    k_gather<<<N_NODES / 4, 256, 0, stream>>>(x, rowptr, col, aggn);
    k_linear<true><<<N_NODES / 32, 256, 0, stream>>>(aggn, x, Wl1, bl1, Wr1, hA);
    // ---- layer 2 ----
    k_gather<<<N_NODES / 4, 256, 0, stream>>>(hA, rowptr, col, aggn);
    k_linear<true><<<N_NODES / 32, 256, 0, stream>>>(aggn, hA, Wl2, bl2, Wr2, hB);
    // ---- layer 3 ----
    k_gather<<<N_NODES / 4, 256, 0, stream>>>(hB, rowptr, col, aggn);
    k_linear<false><<<N_NODES / 32, 256, 0, stream>>>(aggn, hB, Wl3, bl3, Wr3, hA);

    // ---- pool + final linear ----
    hipMemsetAsync(pooled, 0, NGRAPH * DIM * sizeof(float) + NGRAPH * sizeof(float), stream);
    k_pool<<<(N_NODES + 63) / 64, 256, 0, stream>>>(hA, batch, pooled, gcnt);
    k_final<<<1, 128, 0, stream>>>(pooled, gcnt, Wlin, blin, out);
}

// Round 2
// 612.285 us; speedup vs baseline: 1.8636x; 1.8636x over previous
//
#include <hip/hip_runtime.h>

#define N_NODES 100000
#define N_EDGES 1600000
#define DIM 128
#define NGRAPH 64
#define M_PAD 100096  // 782 * 128
#define SCAN_T 256
#define SCAN_BLK 1024
#define NSCAN_BLOCKS ((N_NODES + SCAN_BLK - 1) / SCAN_BLK)  // 98

typedef __attribute__((ext_vector_type(8))) short bf16x8;
typedef __attribute__((ext_vector_type(4))) float floatx4;

static __device__ __forceinline__ unsigned int f2bf(float f) {
    unsigned int u = __builtin_bit_cast(unsigned int, f);
    return (u + 0x7FFFu + ((u >> 16) & 1u)) >> 16;
}
static __device__ __forceinline__ float bf2f(unsigned short b) {
    unsigned int u = ((unsigned int)b) << 16;
    return __builtin_bit_cast(float, u);
}

// ---------------- dtype conversions ----------------

__global__ void k_x2bf(const float* __restrict__ x, unsigned short* __restrict__ xb) {
    size_t i = (size_t)(blockIdx.x * 256 + threadIdx.x) * 4;
    float4 v = *(const float4*)(x + i);
    uint2 o;
    o.x = f2bf(v.x) | (f2bf(v.y) << 16);
    o.y = f2bf(v.z) | (f2bf(v.w) << 16);
    *(uint2*)(xb + i) = o;
}

// Wt[n*256 + k] = (k<128 ? Wl[k][n] : Wr[k-128][n]) as bf16  (k-contiguous per col)
__global__ void k_wcvt(const float* __restrict__ Wl, const float* __restrict__ Wr,
                       unsigned short* __restrict__ Wt) {
    int id = blockIdx.x * 256 + threadIdx.x;  // 32768
    int n = id >> 8, k = id & 255;
    float v = (k < 128) ? Wl[k * 128 + n] : Wr[(k - 128) * 128 + n];
    Wt[n * 256 + k] = (unsigned short)f2bf(v);
}

// ---------------- CSR build ----------------

__global__ void k_count(const int* __restrict__ dst, int* __restrict__ cnt) {
    int e = blockIdx.x * blockDim.x + threadIdx.x;
    if (e < N_EDGES) atomicAdd(&cnt[dst[e]], 1);
}

__global__ void k_scan1(const int* __restrict__ cnt, int* __restrict__ rowptr,
                        int* __restrict__ bsum) {
    __shared__ int s[SCAN_T];
    int tid = threadIdx.x;
    int base = blockIdx.x * SCAN_BLK + tid * 4;
    int v0 = (base + 0 < N_NODES) ? cnt[base + 0] : 0;
    int v1 = (base + 1 < N_NODES) ? cnt[base + 1] : 0;
    int v2 = (base + 2 < N_NODES) ? cnt[base + 2] : 0;
    int v3 = (base + 3 < N_NODES) ? cnt[base + 3] : 0;
    int sum = v0 + v1 + v2 + v3;
    s[tid] = sum;
    __syncthreads();
    for (int off = 1; off < SCAN_T; off <<= 1) {
        int t = (tid >= off) ? s[tid - off] : 0;
        __syncthreads();
        s[tid] += t;
        __syncthreads();
    }
    int run = s[tid] - sum;
    if (base + 0 < N_NODES) rowptr[base + 0] = run; run += v0;
    if (base + 1 < N_NODES) rowptr[base + 1] = run; run += v1;
    if (base + 2 < N_NODES) rowptr[base + 2] = run; run += v2;
    if (base + 3 < N_NODES) rowptr[base + 3] = run;
    if (tid == SCAN_T - 1) bsum[blockIdx.x] = s[tid];
}

__global__ void k_scan2(int* __restrict__ bsum) {
    __shared__ int s[128];
    int tid = threadIdx.x;
    int v = (tid < NSCAN_BLOCKS) ? bsum[tid] : 0;
    s[tid] = v;
    __syncthreads();
    for (int off = 1; off < 128; off <<= 1) {
        int t = (tid >= off) ? s[tid - off] : 0;
        __syncthreads();
        s[tid] += t;
        __syncthreads();
    }
    if (tid < NSCAN_BLOCKS) bsum[tid] = s[tid] - v;
}

__global__ void k_scan3(int* __restrict__ rowptr, const int* __restrict__ bsum) {
    int tid = threadIdx.x;
    int base = blockIdx.x * SCAN_BLK + tid * 4;
    int add = bsum[blockIdx.x];
#pragma unroll
    for (int j = 0; j < 4; j++)
        if (base + j < N_NODES) rowptr[base + j] += add;
    if (blockIdx.x == 0 && tid == 0) rowptr[N_NODES] = N_EDGES;
}

__global__ void k_fill(const int* __restrict__ src, const int* __restrict__ dst,
                       const int* __restrict__ rowptr, int* __restrict__ cursor,
                       int* __restrict__ col) {
    int e = blockIdx.x * blockDim.x + threadIdx.x;
    if (e >= N_EDGES) return;
    int d = dst[e];
    int pos = rowptr[d] + atomicAdd(&cursor[d], 1);
    col[pos] = src[e];
}

// ---------------- mean aggregation, bf16 in/out ----------------
// one wave per node; lane = q*16+t; quarter q handles neighbors c+q, lane t
// covers dims t*8..t*8+7 (16B loads); fp32 accumulate; shfl_xor reduce.

__global__ __launch_bounds__(256) void k_gather_bf(
    const unsigned short* __restrict__ hin, const int* __restrict__ rowptr,
    const int* __restrict__ col, unsigned short* __restrict__ agg) {
    int lane = threadIdx.x & 63;
    int node = blockIdx.x * 4 + (threadIdx.x >> 6);
    int q = lane >> 4, t = lane & 15;
    int start = rowptr[node], end = rowptr[node + 1];
    float acc[8];
#pragma unroll
    for (int j = 0; j < 8; j++) acc[j] = 0.f;

    int c = start + q;
    while (c + 4 < end) {  // two neighbors in flight
        int i0 = col[c];
        int i1 = col[c + 4];
        uint4 v0 = *(const uint4*)(hin + (size_t)i0 * DIM + t * 8);
        uint4 v1 = *(const uint4*)(hin + (size_t)i1 * DIM + t * 8);
        const unsigned int* p0 = &v0.x;
        const unsigned int* p1 = &v1.x;
#pragma unroll
        for (int j = 0; j < 4; j++) {
            acc[2 * j + 0] += bf2f((unsigned short)(p0[j] & 0xFFFF));
            acc[2 * j + 1] += bf2f((unsigned short)(p0[j] >> 16));
            acc[2 * j + 0] += bf2f((unsigned short)(p1[j] & 0xFFFF));
            acc[2 * j + 1] += bf2f((unsigned short)(p1[j] >> 16));
        }
        c += 8;
    }
    if (c < end) {
        int i0 = col[c];
        uint4 v0 = *(const uint4*)(hin + (size_t)i0 * DIM + t * 8);
        const unsigned int* p0 = &v0.x;
#pragma unroll
        for (int j = 0; j < 4; j++) {
            acc[2 * j + 0] += bf2f((unsigned short)(p0[j] & 0xFFFF));
            acc[2 * j + 1] += bf2f((unsigned short)(p0[j] >> 16));
        }
    }
#pragma unroll
    for (int j = 0; j < 8; j++) {
        acc[j] += __shfl_xor(acc[j], 16);
        acc[j] += __shfl_xor(acc[j], 32);
    }
    if (q == 0) {
        int deg = end - start;
        float scale = 1.f / (float)(deg > 0 ? deg : 1);
        uint4 o;
        unsigned int* po = &o.x;
#pragma unroll
        for (int j = 0; j < 4; j++)
            po[j] = f2bf(acc[2 * j] * scale) | (f2bf(acc[2 * j + 1] * scale) << 16);
        *(uint4*)(agg + (size_t)node * DIM + t * 8) = o;
    }
}

// ---------------- fused linear via MFMA ----------------
// hout = act([agg | hin] @ [Wl;Wr] + bl).  Block = 256 thr = 4 waves,
// tile 128 rows x 128 cols; wave w owns cols 32w..32w+31 (2 col-tiles),
// all 16 B-frags in registers, A-frags from global with 1-kstep prefetch.

template <bool RELU>
__global__ __launch_bounds__(256) void k_linear_mfma(
    const unsigned short* __restrict__ aggb, const unsigned short* __restrict__ hb,
    const unsigned short* __restrict__ Wt, const float* __restrict__ bl,
    unsigned short* __restrict__ hout) {
    int tid = threadIdx.x;
    int w = tid >> 6, lane = tid & 63;
    int t = lane & 15, q = lane >> 4;
    size_t i0 = (size_t)blockIdx.x * 128;

    bf16x8 bfrag[2][8];
#pragma unroll
    for (int ct2 = 0; ct2 < 2; ct2++)
#pragma unroll
        for (int ks = 0; ks < 8; ks++)
            bfrag[ct2][ks] =
                *(const bf16x8*)(Wt + (size_t)(w * 32 + ct2 * 16 + t) * 256 + ks * 32 + q * 8);

    floatx4 acc[8][2];
#pragma unroll
    for (int rt = 0; rt < 8; rt++)
#pragma unroll
        for (int c = 0; c < 2; c++) acc[rt][c] = (floatx4){0.f, 0.f, 0.f, 0.f};

    bf16x8 a_cur[8];
#pragma unroll
    for (int rt = 0; rt < 8; rt++)
        a_cur[rt] = *(const bf16x8*)(aggb + (i0 + rt * 16 + t) * DIM + q * 8);

#pragma unroll
    for (int ks = 0; ks < 8; ks++) {
        bf16x8 a_nxt[8];
        if (ks < 7) {
            const unsigned short* base = ((ks + 1) < 4) ? aggb : hb;
            int ko = ((ks + 1) & 3) * 32;
#pragma unroll
            for (int rt = 0; rt < 8; rt++)
                a_nxt[rt] = *(const bf16x8*)(base + (i0 + rt * 16 + t) * DIM + ko + q * 8);
        }
#pragma unroll
        for (int rt = 0; rt < 8; rt++) {
            acc[rt][0] = __builtin_amdgcn_mfma_f32_16x16x32_bf16(a_cur[rt], bfrag[0][ks],
                                                                 acc[rt][0], 0, 0, 0);
            acc[rt][1] = __builtin_amdgcn_mfma_f32_16x16x32_bf16(a_cur[rt], bfrag[1][ks],
                                                                 acc[rt][1], 0, 0, 0);
        }
        if (ks < 7) {
#pragma unroll
            for (int rt = 0; rt < 8; rt++) a_cur[rt] = a_nxt[rt];
        }
    }

    float b0 = bl[w * 32 + t];
    float b1 = bl[w * 32 + 16 + t];
#pragma unroll
    for (int rt = 0; rt < 8; rt++) {
#pragma unroll
        for (int r = 0; r < 4; r++) {
            size_t row = i0 + rt * 16 + q * 4 + r;
            float v0 = acc[rt][0][r] + b0;
            float v1 = acc[rt][1][r] + b1;
            if (RELU) {
                v0 = fmaxf(v0, 0.f);
                v1 = fmaxf(v1, 0.f);
            }
            hout[row * DIM + w * 32 + t] = (unsigned short)f2bf(v0);
            hout[row * DIM + w * 32 + 16 + t] = (unsigned short)f2bf(v1);
        }
    }
}

// ---------------- per-graph mean pool (batch sorted), bf16 input ----------------

__global__ void k_pool(const unsigned short* __restrict__ h, const int* __restrict__ batch,
                       float* __restrict__ pooled, float* __restrict__ gcnt) {
    int tid = threadIdx.x;
    int d = tid & 127, half = tid >> 7;
    int n0 = blockIdx.x * 64 + half * 32;
    if (n0 >= N_NODES) return;
    int nend = n0 + 32;
    if (nend > N_NODES) nend = N_NODES;
    float acc = 0.f;
    int cur = batch[n0];
    int run = 0;
    for (int n = n0; n < nend; n++) {
        int g = batch[n];
        if (g != cur) {
            atomicAdd(&pooled[cur * DIM + d], acc);
            if (d == 0) atomicAdd(&gcnt[cur], (float)run);
            acc = 0.f; run = 0; cur = g;
        }
        acc += bf2f(h[(size_t)n * DIM + d]);
        run++;
    }
    atomicAdd(&pooled[cur * DIM + d], acc);
    if (d == 0) atomicAdd(&gcnt[cur], (float)run);
}

__global__ void k_final(const float* __restrict__ pooled, const float* __restrict__ gcnt,
                        const float* __restrict__ Wlin, const float* __restrict__ blin,
                        float* __restrict__ out) {
    int t = threadIdx.x;  // 128 threads
    int g = t >> 1, o = t & 1;
    float sum = 0.f;
#pragma unroll 8
    for (int k = 0; k < DIM; k++) sum += pooled[g * DIM + k] * Wlin[k * 2 + o];
    float c = gcnt[g];
    out[g * 2 + o] = sum / fmaxf(c, 1.f) + blin[o];
}

// ---------------- launch ----------------

static inline size_t align_up(size_t v, size_t a) { return (v + a - 1) & ~(a - 1); }

extern "C" void kernel_launch(void* const* d_in, const int* in_sizes, int n_in,
                              void* d_out, int out_size, void* d_ws, size_t ws_size,
                              hipStream_t stream) {
    const float* x     = (const float*)d_in[0];
    const int*   ei    = (const int*)d_in[1];
    const int*   src   = ei;
    const int*   dst   = ei + N_EDGES;
    const int*   batch = (const int*)d_in[2];
    const float* Wl1 = (const float*)d_in[3];
    const float* bl1 = (const float*)d_in[4];
    const float* Wr1 = (const float*)d_in[5];
    const float* Wl2 = (const float*)d_in[6];
    const float* bl2 = (const float*)d_in[7];
    const float* Wr2 = (const float*)d_in[8];
    const float* Wl3 = (const float*)d_in[9];
    const float* bl3 = (const float*)d_in[10];
    const float* Wr3 = (const float*)d_in[11];
    const float* Wlin = (const float*)d_in[12];
    const float* blin = (const float*)d_in[13];
    float* out = (float*)d_out;

    char* p = (char*)d_ws;
    size_t off = 0;
    auto carve = [&](size_t bytes) -> void* {
        void* r = p + off;
        off = align_up(off + bytes, 256);
        return r;
    };
    int* rowptr = (int*)carve((N_NODES + 1) * sizeof(int));
    int* cursor = (int*)carve(N_NODES * sizeof(int));
    int* bsum   = (int*)carve(128 * sizeof(int));
    int* col    = (int*)carve((size_t)N_EDGES * sizeof(int));
    unsigned short* bufA = (unsigned short*)carve((size_t)M_PAD * DIM * 2);
    unsigned short* bufB = (unsigned short*)carve((size_t)M_PAD * DIM * 2);
    unsigned short* bufC = (unsigned short*)carve((size_t)M_PAD * DIM * 2);
    unsigned short* agg  = (unsigned short*)carve((size_t)M_PAD * DIM * 2);
    unsigned short* Wt1  = (unsigned short*)carve(256 * 128 * 2);
    unsigned short* Wt2  = (unsigned short*)carve(256 * 128 * 2);
    unsigned short* Wt3  = (unsigned short*)carve(256 * 128 * 2);
    float* pooled = (float*)carve((size_t)NGRAPH * DIM * sizeof(float));
    float* gcnt   = (float*)carve((size_t)NGRAPH * sizeof(float));

    // ---- conversions (independent of CSR) ----
    k_x2bf<<<N_NODES * DIM / 4 / 256, 256, 0, stream>>>(x, bufA);
    k_wcvt<<<128, 256, 0, stream>>>(Wl1, Wr1, Wt1);
    k_wcvt<<<128, 256, 0, stream>>>(Wl2, Wr2, Wt2);
    k_wcvt<<<128, 256, 0, stream>>>(Wl3, Wr3, Wt3);

    // ---- CSR build ----
    hipMemsetAsync(cursor, 0, N_NODES * sizeof(int), stream);
    k_count<<<N_EDGES / 256, 256, 0, stream>>>(dst, cursor);
    k_scan1<<<NSCAN_BLOCKS, SCAN_T, 0, stream>>>(cursor, rowptr, bsum);
    k_scan2<<<1, 128, 0, stream>>>(bsum);
    k_scan3<<<NSCAN_BLOCKS, SCAN_T, 0, stream>>>(rowptr, bsum);
    hipMemsetAsync(cursor, 0, N_NODES * sizeof(int), stream);
    k_fill<<<N_EDGES / 256, 256, 0, stream>>>(src, dst, rowptr, cursor, col);

    const int GRID_G = N_NODES / 4;        // 25000
    const int GRID_L = M_PAD / 128;        // 782

    // ---- layer 1 ----
    k_gather_bf<<<GRID_G, 256, 0, stream>>>(bufA, rowptr, col, agg);
    k_linear_mfma<true><<<GRID_L, 256, 0, stream>>>(agg, bufA, Wt1, bl1, bufB);
    // ---- layer 2 ----
    k_gather_bf<<<GRID_G, 256, 0, stream>>>(bufB, rowptr, col, agg);
    k_linear_mfma<true><<<GRID_L, 256, 0, stream>>>(agg, bufB, Wt2, bl2, bufC);
    // ---- layer 3 ----
    k_gather_bf<<<GRID_G, 256, 0, stream>>>(bufC, rowptr, col, agg);
    k_linear_mfma<false><<<GRID_L, 256, 0, stream>>>(agg, bufC, Wt3, bl3, bufA);

    // ---- pool + final ----
    hipMemsetAsync(pooled, 0, NGRAPH * DIM * sizeof(float) + NGRAPH * sizeof(float), stream);
    k_pool<<<(N_NODES + 63) / 64, 256, 0, stream>>>(bufA, batch, pooled, gcnt);
    k_final<<<1, 128, 0, stream>>>(pooled, gcnt, Wlin, blin, out);
}